// Round 19
// baseline (1076.671 us; speedup 1.0000x reference)
//
#include <hip/hip_runtime.h>
#include <stdint.h>

#define NROWS 32768   // 32*1024
#define DIM   512
#define NEMB  8192

#define BM 128
#define BN 64
#define BK 32
#define MARGIN 1.0e-4f   // validated r6/r7/r9

// ws layout (fast path):
//   [0,        262144) : ull best[NROWS]   key = (f2ord(exact_d)<<32) | idx
//   [262144,   393216) : float x2f[NROWS]
//   [393216,   393224) : double loss_accum
//   [524288,  8912896) : Eb  bf16 swizzled [8192][512]
//   [8912896,42467328) : Xb  bf16 swizzled [32768][512]
#define WS_NEED 42467328ull
//
// Reference model (validated rounds 4-18, PASSED 15x): ref d = fl32(x2-2*M),
// M = k-sequential f32 FMA chain; e2 vanishes under fl32(x2+e2); argmin
// first-occurrence = lowest index on bit-equal d. bf16-hi MFMA selects
// candidates (margin 1e-4); exact f32 chain re-scores -> bit-identical.
//
// r19: OCCUPANCY step 3 -- shrink the accumulator. Ledger: occupancy is the
// only positive lever (19.5->28.9->38.5% = 945->802->766us); at r17 the RF
// is 100% full (16 waves x (64 VGPR + 64 AGPR)). Halve per-wave output to
// 64x32 (acc[4][2]=32 AGPR), tile 128x64, 4 waves, 2 buffers (24.6KB LDS),
// launch_bounds(256,5) -> 20 waves/CU. Schedule = r17's proven two-barrier
// counted-vmcnt (vmcnt(3): 3 issues/wave/tile). Epilogue = r12's validated
// acc[4][2] form. Blocks double (grid 256x128) -- dg-prune absorbs the
// extra epilogues.

typedef short bf16x8 __attribute__((ext_vector_type(8)));   // 8 bf16 (4 VGPRs)
typedef float f32x4  __attribute__((ext_vector_type(4)));

#define LDSP(p) (__attribute__((address_space(3))) unsigned int*)(p)
#define GLP(p)  (const __attribute__((address_space(1))) unsigned int*)(p)

__device__ __forceinline__ unsigned int f2ord(float f) {
    unsigned int b = __float_as_uint(f);
    return b ^ ((b & 0x80000000u) ? 0xFFFFFFFFu : 0x80000000u);
}
__device__ __forceinline__ float ord2f(unsigned int o) {
    unsigned int b = (o & 0x80000000u) ? (o ^ 0x80000000u) : ~o;
    return __uint_as_float(b);
}
__device__ __forceinline__ unsigned short f2b(float f) {   // f32 -> bf16 RNE
    unsigned int u = __float_as_uint(f);
    u += 0x7FFFu + ((u >> 16) & 1u);
    return (unsigned short)(u >> 16);
}

// exact d for (row,col): the reference-matching sequential-k f32 FMA chain.
__device__ __forceinline__ float exact_d(const float* __restrict__ X,
                                         const float* __restrict__ E,
                                         float x2r, int row, int col) {
    const float* xp = X + (size_t)row * DIM;
    const float* ep = E + (size_t)col * DIM;
    float dot = 0.f;
    #pragma unroll 4
    for (int k = 0; k < DIM; k += 4) {
        float4 a  = *(const float4*)(xp + k);
        float4 bb = *(const float4*)(ep + k);
        dot = fmaf(a.x, bb.x, dot); dot = fmaf(a.y, bb.y, dot);
        dot = fmaf(a.z, bb.z, dot); dot = fmaf(a.w, bb.w, dot);
    }
    return x2r - 2.0f * dot;
}

// ||x_row||^2 in f64, rounded to f32 — unchanged (passed 15x)
__global__ __launch_bounds__(256)
void x2_kernel(const float* __restrict__ X, float* __restrict__ x2f) {
    int w = (int)((blockIdx.x * blockDim.x + threadIdx.x) >> 6);
    int lane = threadIdx.x & 63;
    if (w >= NROWS) return;
    const float4* row = (const float4*)(X + (size_t)w * DIM);
    double s = 0.0;
    #pragma unroll
    for (int i = 0; i < 2; ++i) {
        float4 v = row[lane + i * 64];
        s += (double)v.x * v.x + (double)v.y * v.y
           + (double)v.z * v.z + (double)v.w * v.w;
    }
    #pragma unroll
    for (int off = 32; off; off >>= 1) s += __shfl_down(s, off, 64);
    if (lane == 0) x2f[w] = (float)s;
}

// f32 -> bf16 RNE convert with chunk swizzle v2 — unchanged (passed r7-r18)
__global__ __launch_bounds__(256)
void conv_kernel(const float* __restrict__ src, unsigned short* __restrict__ dst,
                 int total) {
    int tid = blockIdx.x * 256 + threadIdx.x;
    if (tid >= total) return;
    int r   = tid >> 6;
    int cg  = tid & 63;
    int seg = cg >> 2, c = cg & 3;
    const float4* s = (const float4*)(src + (size_t)r * DIM + cg * 8);
    float4 v0 = s[0], v1 = s[1];
    unsigned int w0 = (unsigned)f2b(v0.x) | ((unsigned)f2b(v0.y) << 16);
    unsigned int w1 = (unsigned)f2b(v0.z) | ((unsigned)f2b(v0.w) << 16);
    unsigned int w2 = (unsigned)f2b(v1.x) | ((unsigned)f2b(v1.y) << 16);
    unsigned int w3 = (unsigned)f2b(v1.z) | ((unsigned)f2b(v1.w) << 16);
    int dchunk = seg * 4 + (c ^ ((r >> 1) & 3));
    *(uint4*)(dst + (size_t)r * DIM + dchunk * 8) = make_uint4(w0, w1, w2, w3);
}

// 128x64 tile, acc[4][2] (32 AGPR), 5 blocks/CU, r17 counted-vmcnt schedule.
__global__ __launch_bounds__(256, 5)
void dist_mfma10_kernel(const float* __restrict__ X, const float* __restrict__ E,
                        const unsigned short* __restrict__ Xb,
                        const unsigned short* __restrict__ Eb,
                        const float* __restrict__ x2f,
                        unsigned long long* __restrict__ best) {
    __shared__ unsigned short As[2][BM][BK];   // 2 x 8 KB, LINEAR (DMA dest)
    __shared__ unsigned short Bs[2][BN][BK];   // 2 x 4 KB
    __shared__ unsigned int   smin[BM];

    const int t    = threadIdx.x;
    const int lane = t & 63;
    const int wid  = t >> 6;
    const int wm   = (wid >> 1) * 64;          // 2 M-halves
    const int wn   = (wid & 1) * 32;           // 2 N-halves of 64-col tile
    const int rowBase = blockIdx.x * BM;   // x = row panels (fast) -> warm prune
    const int colBase = blockIdx.y * BN;

    if (t < BM) smin[t] = 0xFFFFFFFFu;

    // A staging: wave wid covers rows wid*16..+15 (plus +64 twin); 2 issues.
    const char* aSrc = (const char*)Xb
        + (size_t)(rowBase + wid * 16 + (lane >> 2)) * 1024 + (size_t)(lane & 3) * 16;
    // B staging: 64 rows total; wave wid covers rows wid*16..+15; 1 issue.
    const char* bSrc = (const char*)Eb
        + (size_t)(colBase + wid * 16 + (lane >> 2)) * 1024 + (size_t)(lane & 3) * 16;

    // fragment read: row = base + (lane&15); logical chunk koff=(lane>>4) at
    // physical slot koff ^ ((row>>1)&3) = koff ^ ((lane>>1)&3)  [r7-validated]
    const int fswz = (((lane >> 4) ^ ((lane >> 1) & 3)) << 4);
    const int aOff = (wm + (lane & 15)) * 64 + fswz;
    const int bOff = (wn + (lane & 15)) * 64 + fswz;

    f32x4 acc[4][2] = {};

#define ISSUE_TILE(KT, BUF) do {                                               \
        const char* an_ = aSrc + (KT) * 64;                                    \
        const char* bn_ = bSrc + (KT) * 64;                                    \
        __builtin_amdgcn_global_load_lds(GLP(an_),         LDSP(&As[BUF][wid * 16][0]),      16, 0, 0); \
        __builtin_amdgcn_global_load_lds(GLP(an_ + 65536), LDSP(&As[BUF][64 + wid * 16][0]), 16, 0, 0); \
        __builtin_amdgcn_global_load_lds(GLP(bn_),         LDSP(&Bs[BUF][wid * 16][0]),      16, 0, 0); \
    } while (0)

#define COMPUTE_TILE(BUF) do {                                                 \
        const char* aR_ = (const char*)&As[BUF][0][0] + aOff;                  \
        const char* bR_ = (const char*)&Bs[BUF][0][0] + bOff;                  \
        bf16x8 af_[4], bg_[2];                                                 \
        _Pragma("unroll")                                                      \
        for (int mi = 0; mi < 4; ++mi)                                         \
            af_[mi] = *(const bf16x8*)(aR_ + mi * 16 * 64);                    \
        _Pragma("unroll")                                                      \
        for (int nj = 0; nj < 2; ++nj)                                         \
            bg_[nj] = *(const bf16x8*)(bR_ + nj * 16 * 64);                    \
        _Pragma("unroll")                                                      \
        for (int mi = 0; mi < 4; ++mi)                                         \
            _Pragma("unroll")                                                  \
            for (int nj = 0; nj < 2; ++nj)                                     \
                acc[mi][nj] = __builtin_amdgcn_mfma_f32_16x16x32_bf16(         \
                    af_[mi], bg_[nj], acc[mi][nj], 0, 0, 0);                   \
    } while (0)

// Step KT (r17 schedule): issue KT+1 (3 loads) into buf (KT+1)&1 (released by
// step KT-1's trailing lgkmcnt(0)+barrier); counted vmcnt(3) retires exactly
// tile KT (outstanding: KT(3) + KT+1(3) = 6 -> wait 3); barrier; compute;
// lgkmcnt(0)+barrier protects buf for the next step's DMA.
#define K_STEP(KT, WAITSTR) do {                                               \
        if ((KT) + 1 < 16) ISSUE_TILE((KT) + 1, ((KT) + 1) & 1);               \
        asm volatile("s_waitcnt vmcnt(" WAITSTR ")" ::: "memory");             \
        __builtin_amdgcn_s_barrier();                                          \
        COMPUTE_TILE((KT) & 1);                                                \
        asm volatile("s_waitcnt lgkmcnt(0)" ::: "memory");                     \
        __builtin_amdgcn_s_barrier();                                          \
    } while (0)

    ISSUE_TILE(0, 0);

    K_STEP(0,  "3");  K_STEP(1,  "3");  K_STEP(2,  "3");  K_STEP(3,  "3");
    K_STEP(4,  "3");  K_STEP(5,  "3");  K_STEP(6,  "3");  K_STEP(7,  "3");
    K_STEP(8,  "3");  K_STEP(9,  "3");  K_STEP(10, "3");  K_STEP(11, "3");
    K_STEP(12, "3");  K_STEP(13, "3");  K_STEP(14, "3");  K_STEP(15, "0");

#undef K_STEP
#undef COMPUTE_TILE
#undef ISSUE_TILE

    // ---- block-local per-row min of s~ = -2*acc (r12's acc[4][2] form) ----
    #pragma unroll
    for (int mi = 0; mi < 4; ++mi)
        #pragma unroll
        for (int r = 0; r < 4; ++r) {
            float m2 = fminf(-2.f * acc[mi][0][r], -2.f * acc[mi][1][r]);
            unsigned u = f2ord(m2);
            #pragma unroll
            for (int sh = 1; sh < 16; sh <<= 1)
                u = min(u, (unsigned)__shfl_xor((int)u, sh, 64));
            if ((lane & 15) == 0)
                atomicMin(&smin[wm + mi * 16 + (lane >> 4) * 4 + r], u);
        }
    __syncthreads();

    // ---- candidate mask: s~ <= min(block_min, global_best - x2) + MARGIN ----
    unsigned mask = 0;
    #pragma unroll
    for (int mi = 0; mi < 4; ++mi)
        #pragma unroll
        for (int r = 0; r < 4; ++r) {
            int rt  = wm + mi * 16 + (lane >> 4) * 4 + r;
            int row = rowBase + rt;
            float x2v = x2f[row];
            float dg  = ord2f((unsigned)(best[row] >> 32));   // NaN if sentinel
            float th  = fminf(ord2f(smin[rt]), dg - x2v) + MARGIN;  // NaN-safe
            #pragma unroll
            for (int nj = 0; nj < 2; ++nj) {
                float s = -2.f * acc[mi][nj][r];
                if (s <= th) mask |= 1u << (mi * 8 + nj * 4 + r);
            }
        }

    // ---- exact refine (bit-identical chain, passed 15x) ----
    while (mask) {
        int b = __builtin_ctz(mask);
        mask &= mask - 1;
        int mi = b >> 3, nj = (b >> 2) & 1, r = b & 3;
        int row = rowBase + wm + mi * 16 + (lane >> 4) * 4 + r;
        int col = colBase + wn + nj * 16 + (lane & 15);
        float d = exact_d(X, E, x2f[row], row, col);
        unsigned long long key = ((unsigned long long)f2ord(d) << 32) | (unsigned)col;
        atomicMin(&best[row], key);
    }
}

// ---------- round-5 kernel kept as last-resort fallback (tiny ws) ----------
__global__ __launch_bounds__(256)
void dist_mfma_kernel(const float* __restrict__ X, const float* __restrict__ E,
                      const float* __restrict__ x2f,
                      unsigned long long* __restrict__ best) {
    __shared__ unsigned short Asf[BM][40];
    __shared__ unsigned short Bsf[128][40];
    __shared__ unsigned int   smin[BM];

    const int t    = threadIdx.x;
    const int lane = t & 63;
    const int wid  = t >> 6;
    const int wm   = (wid >> 1) * 64;
    const int wn   = (wid & 1) * 64;
    const int rowBase = blockIdx.x * BM;
    const int colBase = blockIdx.y * 128;

    if (t < BM) smin[t] = 0xFFFFFFFFu;

    const int srow = t >> 3;
    const int sf4  = t & 7;

    f32x4 acc[4][4] = {};
    float4 ra[4], rb[4];

    #pragma unroll
    for (int p = 0; p < 4; ++p) {
        ra[p] = *(const float4*)(X + (size_t)(rowBase + p * 32 + srow) * DIM + sf4 * 4);
        rb[p] = *(const float4*)(E + (size_t)(colBase + p * 32 + srow) * DIM + sf4 * 4);
    }

    for (int kt = 0; kt < DIM / BK; ++kt) {
        __syncthreads();
        #pragma unroll
        for (int p = 0; p < 4; ++p) {
            int r = p * 32 + srow;
            unsigned int alo = (unsigned)f2b(ra[p].x) | ((unsigned)f2b(ra[p].y) << 16);
            unsigned int ahi = (unsigned)f2b(ra[p].z) | ((unsigned)f2b(ra[p].w) << 16);
            *(uint2*)&Asf[r][sf4 * 4] = make_uint2(alo, ahi);
            unsigned int blo = (unsigned)f2b(rb[p].x) | ((unsigned)f2b(rb[p].y) << 16);
            unsigned int bhi = (unsigned)f2b(rb[p].z) | ((unsigned)f2b(rb[p].w) << 16);
            *(uint2*)&Bsf[r][sf4 * 4] = make_uint2(blo, bhi);
        }
        __syncthreads();

        if (kt + 1 < DIM / BK) {
            int k0 = (kt + 1) * BK;
            #pragma unroll
            for (int p = 0; p < 4; ++p) {
                ra[p] = *(const float4*)(X + (size_t)(rowBase + p * 32 + srow) * DIM + k0 + sf4 * 4);
                rb[p] = *(const float4*)(E + (size_t)(colBase + p * 32 + srow) * DIM + k0 + sf4 * 4);
            }
        }

        bf16x8 af[4], bg[4];
        #pragma unroll
        for (int mi = 0; mi < 4; ++mi)
            af[mi] = *(const bf16x8*)&Asf[wm + mi * 16 + (lane & 15)][(lane >> 4) * 8];
        #pragma unroll
        for (int nj = 0; nj < 4; ++nj)
            bg[nj] = *(const bf16x8*)&Bsf[wn + nj * 16 + (lane & 15)][(lane >> 4) * 8];
        #pragma unroll
        for (int mi = 0; mi < 4; ++mi)
            #pragma unroll
            for (int nj = 0; nj < 4; ++nj)
                acc[mi][nj] = __builtin_amdgcn_mfma_f32_16x16x32_bf16(
                    af[mi], bg[nj], acc[mi][nj], 0, 0, 0);
    }

    #pragma unroll
    for (int mi = 0; mi < 4; ++mi)
        #pragma unroll
        for (int r = 0; r < 4; ++r) {
            float m4 = fminf(fminf(-2.f * acc[mi][0][r], -2.f * acc[mi][1][r]),
                             fminf(-2.f * acc[mi][2][r], -2.f * acc[mi][3][r]));
            unsigned u = f2ord(m4);
            #pragma unroll
            for (int sh = 1; sh < 16; sh <<= 1)
                u = min(u, (unsigned)__shfl_xor((int)u, sh, 64));
            if ((lane & 15) == 0)
                atomicMin(&smin[wm + mi * 16 + (lane >> 4) * 4 + r], u);
        }
    __syncthreads();

    unsigned long long mask = 0;
    #pragma unroll
    for (int mi = 0; mi < 4; ++mi)
        #pragma unroll
        for (int r = 0; r < 4; ++r) {
            int rt  = wm + mi * 16 + (lane >> 4) * 4 + r;
            int row = rowBase + rt;
            float x2v = x2f[row];
            float dg  = ord2f((unsigned)(best[row] >> 32));
            float th  = fminf(ord2f(smin[rt]), dg - x2v) + 1.5e-3f;
            #pragma unroll
            for (int nj = 0; nj < 4; ++nj) {
                float s = -2.f * acc[mi][nj][r];
                if (s <= th) mask |= 1ull << (mi * 16 + nj * 4 + r);
            }
        }

    while (mask) {
        int b = __builtin_ctzll(mask);
        mask &= mask - 1;
        int mi = b >> 4, nj = (b >> 2) & 3, r = b & 3;
        int row = rowBase + wm + mi * 16 + (lane >> 4) * 4 + r;
        int col = colBase + wn + nj * 16 + (lane & 15);
        float d = exact_d(X, E, x2f[row], row, col);
        unsigned long long key = ((unsigned long long)f2ord(d) << 32) | (unsigned)col;
        atomicMin(&best[row], key);
    }
}

// gather quantized + accumulate squared-error loss — unchanged (passed 15x)
__global__ __launch_bounds__(256)
void gather_loss_kernel(const float* __restrict__ X, const float* __restrict__ E,
                        const unsigned long long* __restrict__ best,
                        float* __restrict__ out_q, double* __restrict__ accum) {
    __shared__ float wsum[4];
    const int t = threadIdx.x;
    const size_t base = (size_t)blockIdx.x * 8192;
    float local = 0.f;
    #pragma unroll 4
    for (int it = 0; it < 32; ++it) {
        size_t i = base + (size_t)it * 256 + t;
        int row = (int)(i >> 9);
        int d   = (int)(i & 511);
        unsigned int idx = (unsigned int)(best[row] & 0xFFFFFFFFull);
        float q = E[(size_t)idx * DIM + d];
        float x = X[i];
        out_q[i] = q;
        float df = q - x;
        local = fmaf(df, df, local);
    }
    #pragma unroll
    for (int off = 32; off; off >>= 1) local += __shfl_down(local, off, 64);
    int lane = t & 63, w = t >> 6;
    if (lane == 0) wsum[w] = local;
    __syncthreads();
    if (t == 0) {
        float s = wsum[0] + wsum[1] + wsum[2] + wsum[3];
        atomicAdd(accum, (double)s);
    }
}

__global__ __launch_bounds__(256)
void finalize_kernel(const unsigned long long* __restrict__ best,
                     float* __restrict__ out_idx, float* __restrict__ out_loss,
                     const double* __restrict__ accum) {
    int r = blockIdx.x * blockDim.x + threadIdx.x;
    if (r < NROWS) out_idx[r] = (float)(unsigned int)(best[r] & 0xFFFFFFFFull);
    if (r == 0) out_loss[0] = (float)(1.25 * (*accum) / 16777216.0);
}

extern "C" void kernel_launch(void* const* d_in, const int* in_sizes, int n_in,
                              void* d_out, int out_size, void* d_ws, size_t ws_size,
                              hipStream_t stream) {
    const float* X = (const float*)d_in[0];   // [32,1024,512] f32
    const float* E = (const float*)d_in[1];   // [8192,512]    f32

    float* out      = (float*)d_out;
    float* out_q    = out;                          // 16777216
    float* out_idx  = out + (size_t)NROWS * DIM;    // 32768
    float* out_loss = out_idx + NROWS;              // 1

    char* ws = (char*)d_ws;
    unsigned long long* best = (unsigned long long*)ws;
    float*  x2f   = (float*)(ws + 262144);
    double* accum = (double*)(ws + 393216);

    hipMemsetAsync(best, 0xFF, (size_t)NROWS * 8, stream);
    hipMemsetAsync(accum, 0, 8, stream);

    x2_kernel<<<NROWS / 4, 256, 0, stream>>>(X, x2f);

    if (ws_size >= WS_NEED) {
        unsigned short* Eb = (unsigned short*)(ws + 524288);
        unsigned short* Xb = (unsigned short*)(ws + 8912896);
        conv_kernel<<<(NEMB * 64) / 256, 256, 0, stream>>>(E, Eb, NEMB * 64);
        conv_kernel<<<(NROWS * 64) / 256, 256, 0, stream>>>(X, Xb, NROWS * 64);
        dim3 gridB(NROWS / BM, NEMB / BN);   // 256 x 128, x = row panels (fast)
        dist_mfma10_kernel<<<gridB, 256, 0, stream>>>(X, E, Xb, Eb, x2f, best);
    } else {
        dim3 gridB(NROWS / BM, NEMB / 128);
        dist_mfma_kernel<<<gridB, 256, 0, stream>>>(X, E, x2f, best);
    }

    gather_loss_kernel<<<2048, 256, 0, stream>>>(X, E, best, out_q, accum);
    finalize_kernel<<<NROWS / 256, 256, 0, stream>>>(best, out_idx, out_loss, accum);
}

// Round 20
// 790.006 us; speedup vs baseline: 1.3629x; 1.3629x over previous
//
#include <hip/hip_runtime.h>
#include <stdint.h>

#define NROWS 32768   // 32*1024
#define DIM   512
#define NEMB  8192

#define BM 128
#define BN 256
#define BK 32
#define MARGIN 1.0e-4f   // validated r6/r7/r9

// ws layout (fast path):
//   [0,        262144) : ull best[NROWS]   key = (f2ord(exact_d)<<32) | idx
//   [262144,   393216) : float x2f[NROWS]
//   [393216,   393224) : double loss_accum
//   [524288,  8912896) : Eb  bf16 swizzled [8192][512]
//   [8912896,42467328) : Xb  bf16 swizzled [32768][512]
#define WS_NEED 42467328ull
//
// Reference model (validated rounds 4-19, PASSED 16x): ref d = fl32(x2-2*M),
// M = k-sequential f32 FMA chain; e2 vanishes under fl32(x2+e2); argmin
// first-occurrence = lowest index on bit-equal d. bf16-hi MFMA selects
// candidates (margin 1e-4); exact f32 chain re-scores -> bit-identical.
//
// r20: work-per-sync at constant RF pressure. Session law: throughput ~
// (waves/CU x MFMA-per-wave-per-sync) / sync-cost. r17 = 16 waves x 16
// MFMA/step (766us); r19 kept waves, halved work/step -> 1046us. r20:
// 8-wave blocks, 128x256 tile, per-wave output still 64x64 (r17's exact
// register shape: 64 VGPR + 64 AGPR). Per CU: 2 blocks = 16 waves (r17-
// equal), LDS 96KB, per-step MFMA equal -- but HALF the block-steps,
// HALF the barriers/vmcnt waits, HALF the epilogues, A-traffic halved.
// Schedule/swizzle/epilogue byte-identical to r17; 3 DMA issues/wave/tile
// (A:1, B:2) -> vmcnt(3). launch_bounds(512,4) = 128-reg cap, 2 blocks/CU.

typedef short bf16x8 __attribute__((ext_vector_type(8)));   // 8 bf16 (4 VGPRs)
typedef float f32x4  __attribute__((ext_vector_type(4)));

#define LDSP(p) (__attribute__((address_space(3))) unsigned int*)(p)
#define GLP(p)  (const __attribute__((address_space(1))) unsigned int*)(p)

__device__ __forceinline__ unsigned int f2ord(float f) {
    unsigned int b = __float_as_uint(f);
    return b ^ ((b & 0x80000000u) ? 0xFFFFFFFFu : 0x80000000u);
}
__device__ __forceinline__ float ord2f(unsigned int o) {
    unsigned int b = (o & 0x80000000u) ? (o ^ 0x80000000u) : ~o;
    return __uint_as_float(b);
}
__device__ __forceinline__ unsigned short f2b(float f) {   // f32 -> bf16 RNE
    unsigned int u = __float_as_uint(f);
    u += 0x7FFFu + ((u >> 16) & 1u);
    return (unsigned short)(u >> 16);
}

// exact d for (row,col): the reference-matching sequential-k f32 FMA chain.
__device__ __forceinline__ float exact_d(const float* __restrict__ X,
                                         const float* __restrict__ E,
                                         float x2r, int row, int col) {
    const float* xp = X + (size_t)row * DIM;
    const float* ep = E + (size_t)col * DIM;
    float dot = 0.f;
    #pragma unroll 4
    for (int k = 0; k < DIM; k += 4) {
        float4 a  = *(const float4*)(xp + k);
        float4 bb = *(const float4*)(ep + k);
        dot = fmaf(a.x, bb.x, dot); dot = fmaf(a.y, bb.y, dot);
        dot = fmaf(a.z, bb.z, dot); dot = fmaf(a.w, bb.w, dot);
    }
    return x2r - 2.0f * dot;
}

// ||x_row||^2 in f64, rounded to f32 — unchanged (passed 16x)
__global__ __launch_bounds__(256)
void x2_kernel(const float* __restrict__ X, float* __restrict__ x2f) {
    int w = (int)((blockIdx.x * blockDim.x + threadIdx.x) >> 6);
    int lane = threadIdx.x & 63;
    if (w >= NROWS) return;
    const float4* row = (const float4*)(X + (size_t)w * DIM);
    double s = 0.0;
    #pragma unroll
    for (int i = 0; i < 2; ++i) {
        float4 v = row[lane + i * 64];
        s += (double)v.x * v.x + (double)v.y * v.y
           + (double)v.z * v.z + (double)v.w * v.w;
    }
    #pragma unroll
    for (int off = 32; off; off >>= 1) s += __shfl_down(s, off, 64);
    if (lane == 0) x2f[w] = (float)s;
}

// f32 -> bf16 RNE convert with chunk swizzle v2 — unchanged (passed r7-r19)
__global__ __launch_bounds__(256)
void conv_kernel(const float* __restrict__ src, unsigned short* __restrict__ dst,
                 int total) {
    int tid = blockIdx.x * 256 + threadIdx.x;
    if (tid >= total) return;
    int r   = tid >> 6;
    int cg  = tid & 63;
    int seg = cg >> 2, c = cg & 3;
    const float4* s = (const float4*)(src + (size_t)r * DIM + cg * 8);
    float4 v0 = s[0], v1 = s[1];
    unsigned int w0 = (unsigned)f2b(v0.x) | ((unsigned)f2b(v0.y) << 16);
    unsigned int w1 = (unsigned)f2b(v0.z) | ((unsigned)f2b(v0.w) << 16);
    unsigned int w2 = (unsigned)f2b(v1.x) | ((unsigned)f2b(v1.y) << 16);
    unsigned int w3 = (unsigned)f2b(v1.z) | ((unsigned)f2b(v1.w) << 16);
    int dchunk = seg * 4 + (c ^ ((r >> 1) & 3));
    *(uint4*)(dst + (size_t)r * DIM + dchunk * 8) = make_uint4(w0, w1, w2, w3);
}

// 128x256 tile, 8 waves (each 64x64 out, r17's register shape), 2 blocks/CU.
__global__ __launch_bounds__(512, 4)
void dist_mfma11_kernel(const float* __restrict__ X, const float* __restrict__ E,
                        const unsigned short* __restrict__ Xb,
                        const unsigned short* __restrict__ Eb,
                        const float* __restrict__ x2f,
                        unsigned long long* __restrict__ best) {
    __shared__ unsigned short As[2][BM][BK];   // 2 x 8 KB, LINEAR (DMA dest)
    __shared__ unsigned short Bs[2][BN][BK];   // 2 x 16 KB
    __shared__ unsigned int   smin[BM];

    const int t    = threadIdx.x;
    const int lane = t & 63;
    const int wid  = t >> 6;                   // 0..7
    const int wm   = (wid >> 2) * 64;          // 2 M-halves
    const int wn   = (wid & 3) * 64;           // 4 N-quarters
    const int rowBase = blockIdx.x * BM;   // x = row panels (fast) -> warm prune
    const int colBase = blockIdx.y * BN;

    if (t < BM) smin[t] = 0xFFFFFFFFu;

    // A staging: 128 rows; 8 waves x 16 rows -> 1 issue/wave.
    const char* aSrc = (const char*)Xb
        + (size_t)(rowBase + wid * 16 + (lane >> 2)) * 1024 + (size_t)(lane & 3) * 16;
    // B staging: 256 rows; rows wid*16+(lane>>2) and +128 -> 2 issues/wave.
    const char* bSrc = (const char*)Eb
        + (size_t)(colBase + wid * 16 + (lane >> 2)) * 1024 + (size_t)(lane & 3) * 16;

    // fragment read: row = base + (lane&15); logical chunk koff=(lane>>4) at
    // physical slot koff ^ ((row>>1)&3) = koff ^ ((lane>>1)&3)  [r7-validated]
    const int fswz = (((lane >> 4) ^ ((lane >> 1) & 3)) << 4);
    const int aOff = (wm + (lane & 15)) * 64 + fswz;
    const int bOff = (wn + (lane & 15)) * 64 + fswz;

    f32x4 acc[4][4] = {};

#define ISSUE_TILE(KT, BUF) do {                                               \
        const char* an_ = aSrc + (KT) * 64;                                    \
        const char* bn_ = bSrc + (KT) * 64;                                    \
        __builtin_amdgcn_global_load_lds(GLP(an_),          LDSP(&As[BUF][wid * 16][0]),       16, 0, 0); \
        __builtin_amdgcn_global_load_lds(GLP(bn_),          LDSP(&Bs[BUF][wid * 16][0]),       16, 0, 0); \
        __builtin_amdgcn_global_load_lds(GLP(bn_ + 131072), LDSP(&Bs[BUF][128 + wid * 16][0]), 16, 0, 0); \
    } while (0)

#define COMPUTE_TILE(BUF) do {                                                 \
        const char* aR_ = (const char*)&As[BUF][0][0] + aOff;                  \
        const char* bR_ = (const char*)&Bs[BUF][0][0] + bOff;                  \
        bf16x8 af_[4], bg_[4];                                                 \
        _Pragma("unroll")                                                      \
        for (int mi = 0; mi < 4; ++mi)                                         \
            af_[mi] = *(const bf16x8*)(aR_ + mi * 16 * 64);                    \
        _Pragma("unroll")                                                      \
        for (int nj = 0; nj < 4; ++nj)                                         \
            bg_[nj] = *(const bf16x8*)(bR_ + nj * 16 * 64);                    \
        _Pragma("unroll")                                                      \
        for (int mi = 0; mi < 4; ++mi)                                         \
            _Pragma("unroll")                                                  \
            for (int nj = 0; nj < 4; ++nj)                                     \
                acc[mi][nj] = __builtin_amdgcn_mfma_f32_16x16x32_bf16(         \
                    af_[mi], bg_[nj], acc[mi][nj], 0, 0, 0);                   \
    } while (0)

// Step KT (r17 schedule, 3 loads/tile): issue KT+1 into buf (KT+1)&1
// (released by step KT-1's trailing lgkmcnt(0)+barrier); counted vmcnt(3)
// retires exactly tile KT; barrier; compute; lgkmcnt(0)+barrier.
#define K_STEP(KT, WAITSTR) do {                                               \
        if ((KT) + 1 < 16) ISSUE_TILE((KT) + 1, ((KT) + 1) & 1);               \
        asm volatile("s_waitcnt vmcnt(" WAITSTR ")" ::: "memory");             \
        __builtin_amdgcn_s_barrier();                                          \
        COMPUTE_TILE((KT) & 1);                                                \
        asm volatile("s_waitcnt lgkmcnt(0)" ::: "memory");                     \
        __builtin_amdgcn_s_barrier();                                          \
    } while (0)

    ISSUE_TILE(0, 0);

    K_STEP(0,  "3");  K_STEP(1,  "3");  K_STEP(2,  "3");  K_STEP(3,  "3");
    K_STEP(4,  "3");  K_STEP(5,  "3");  K_STEP(6,  "3");  K_STEP(7,  "3");
    K_STEP(8,  "3");  K_STEP(9,  "3");  K_STEP(10, "3");  K_STEP(11, "3");
    K_STEP(12, "3");  K_STEP(13, "3");  K_STEP(14, "3");  K_STEP(15, "0");

#undef K_STEP
#undef COMPUTE_TILE
#undef ISSUE_TILE

    // ---- block-local per-row min of s~ = -2*acc (r17 verbatim) ----
    #pragma unroll
    for (int mi = 0; mi < 4; ++mi)
        #pragma unroll
        for (int r = 0; r < 4; ++r) {
            float m4 = fminf(fminf(-2.f * acc[mi][0][r], -2.f * acc[mi][1][r]),
                             fminf(-2.f * acc[mi][2][r], -2.f * acc[mi][3][r]));
            unsigned u = f2ord(m4);
            #pragma unroll
            for (int sh = 1; sh < 16; sh <<= 1)
                u = min(u, (unsigned)__shfl_xor((int)u, sh, 64));
            if ((lane & 15) == 0)
                atomicMin(&smin[wm + mi * 16 + (lane >> 4) * 4 + r], u);
        }
    __syncthreads();

    // ---- candidate mask: s~ <= min(block_min, global_best - x2) + MARGIN ----
    unsigned long long mask = 0;
    #pragma unroll
    for (int mi = 0; mi < 4; ++mi)
        #pragma unroll
        for (int r = 0; r < 4; ++r) {
            int rt  = wm + mi * 16 + (lane >> 4) * 4 + r;
            int row = rowBase + rt;
            float x2v = x2f[row];
            float dg  = ord2f((unsigned)(best[row] >> 32));   // NaN if sentinel
            float th  = fminf(ord2f(smin[rt]), dg - x2v) + MARGIN;  // NaN-safe
            #pragma unroll
            for (int nj = 0; nj < 4; ++nj) {
                float s = -2.f * acc[mi][nj][r];
                if (s <= th) mask |= 1ull << (mi * 16 + nj * 4 + r);
            }
        }

    // ---- exact refine (bit-identical chain, passed 16x) ----
    while (mask) {
        int b = __builtin_ctzll(mask);
        mask &= mask - 1;
        int mi = b >> 4, nj = (b >> 2) & 3, r = b & 3;
        int row = rowBase + wm + mi * 16 + (lane >> 4) * 4 + r;
        int col = colBase + wn + nj * 16 + (lane & 15);
        float d = exact_d(X, E, x2f[row], row, col);
        unsigned long long key = ((unsigned long long)f2ord(d) << 32) | (unsigned)col;
        atomicMin(&best[row], key);
    }
}

// ---------- round-5 kernel kept as last-resort fallback (tiny ws) ----------
__global__ __launch_bounds__(256)
void dist_mfma_kernel(const float* __restrict__ X, const float* __restrict__ E,
                      const float* __restrict__ x2f,
                      unsigned long long* __restrict__ best) {
    __shared__ unsigned short Asf[BM][40];
    __shared__ unsigned short Bsf[128][40];
    __shared__ unsigned int   smin[BM];

    const int t    = threadIdx.x;
    const int lane = t & 63;
    const int wid  = t >> 6;
    const int wm   = (wid >> 1) * 64;
    const int wn   = (wid & 1) * 64;
    const int rowBase = blockIdx.x * BM;
    const int colBase = blockIdx.y * 128;

    if (t < BM) smin[t] = 0xFFFFFFFFu;

    const int srow = t >> 3;
    const int sf4  = t & 7;

    f32x4 acc[4][4] = {};
    float4 ra[4], rb[4];

    #pragma unroll
    for (int p = 0; p < 4; ++p) {
        ra[p] = *(const float4*)(X + (size_t)(rowBase + p * 32 + srow) * DIM + sf4 * 4);
        rb[p] = *(const float4*)(E + (size_t)(colBase + p * 32 + srow) * DIM + sf4 * 4);
    }

    for (int kt = 0; kt < DIM / BK; ++kt) {
        __syncthreads();
        #pragma unroll
        for (int p = 0; p < 4; ++p) {
            int r = p * 32 + srow;
            unsigned int alo = (unsigned)f2b(ra[p].x) | ((unsigned)f2b(ra[p].y) << 16);
            unsigned int ahi = (unsigned)f2b(ra[p].z) | ((unsigned)f2b(ra[p].w) << 16);
            *(uint2*)&Asf[r][sf4 * 4] = make_uint2(alo, ahi);
            unsigned int blo = (unsigned)f2b(rb[p].x) | ((unsigned)f2b(rb[p].y) << 16);
            unsigned int bhi = (unsigned)f2b(rb[p].z) | ((unsigned)f2b(rb[p].w) << 16);
            *(uint2*)&Bsf[r][sf4 * 4] = make_uint2(blo, bhi);
        }
        __syncthreads();

        if (kt + 1 < DIM / BK) {
            int k0 = (kt + 1) * BK;
            #pragma unroll
            for (int p = 0; p < 4; ++p) {
                ra[p] = *(const float4*)(X + (size_t)(rowBase + p * 32 + srow) * DIM + k0 + sf4 * 4);
                rb[p] = *(const float4*)(E + (size_t)(colBase + p * 32 + srow) * DIM + k0 + sf4 * 4);
            }
        }

        bf16x8 af[4], bg[4];
        #pragma unroll
        for (int mi = 0; mi < 4; ++mi)
            af[mi] = *(const bf16x8*)&Asf[wm + mi * 16 + (lane & 15)][(lane >> 4) * 8];
        #pragma unroll
        for (int nj = 0; nj < 4; ++nj)
            bg[nj] = *(const bf16x8*)&Bsf[wn + nj * 16 + (lane & 15)][(lane >> 4) * 8];
        #pragma unroll
        for (int mi = 0; mi < 4; ++mi)
            #pragma unroll
            for (int nj = 0; nj < 4; ++nj)
                acc[mi][nj] = __builtin_amdgcn_mfma_f32_16x16x32_bf16(
                    af[mi], bg[nj], acc[mi][nj], 0, 0, 0);
    }

    #pragma unroll
    for (int mi = 0; mi < 4; ++mi)
        #pragma unroll
        for (int r = 0; r < 4; ++r) {
            float m4 = fminf(fminf(-2.f * acc[mi][0][r], -2.f * acc[mi][1][r]),
                             fminf(-2.f * acc[mi][2][r], -2.f * acc[mi][3][r]));
            unsigned u = f2ord(m4);
            #pragma unroll
            for (int sh = 1; sh < 16; sh <<= 1)
                u = min(u, (unsigned)__shfl_xor((int)u, sh, 64));
            if ((lane & 15) == 0)
                atomicMin(&smin[wm + mi * 16 + (lane >> 4) * 4 + r], u);
        }
    __syncthreads();

    unsigned long long mask = 0;
    #pragma unroll
    for (int mi = 0; mi < 4; ++mi)
        #pragma unroll
        for (int r = 0; r < 4; ++r) {
            int rt  = wm + mi * 16 + (lane >> 4) * 4 + r;
            int row = rowBase + rt;
            float x2v = x2f[row];
            float dg  = ord2f((unsigned)(best[row] >> 32));
            float th  = fminf(ord2f(smin[rt]), dg - x2v) + 1.5e-3f;
            #pragma unroll
            for (int nj = 0; nj < 4; ++nj) {
                float s = -2.f * acc[mi][nj][r];
                if (s <= th) mask |= 1ull << (mi * 16 + nj * 4 + r);
            }
        }

    while (mask) {
        int b = __builtin_ctzll(mask);
        mask &= mask - 1;
        int mi = b >> 4, nj = (b >> 2) & 3, r = b & 3;
        int row = rowBase + wm + mi * 16 + (lane >> 4) * 4 + r;
        int col = colBase + wn + nj * 16 + (lane & 15);
        float d = exact_d(X, E, x2f[row], row, col);
        unsigned long long key = ((unsigned long long)f2ord(d) << 32) | (unsigned)col;
        atomicMin(&best[row], key);
    }
}

// gather quantized + accumulate squared-error loss — unchanged (passed 16x)
__global__ __launch_bounds__(256)
void gather_loss_kernel(const float* __restrict__ X, const float* __restrict__ E,
                        const unsigned long long* __restrict__ best,
                        float* __restrict__ out_q, double* __restrict__ accum) {
    __shared__ float wsum[4];
    const int t = threadIdx.x;
    const size_t base = (size_t)blockIdx.x * 8192;
    float local = 0.f;
    #pragma unroll 4
    for (int it = 0; it < 32; ++it) {
        size_t i = base + (size_t)it * 256 + t;
        int row = (int)(i >> 9);
        int d   = (int)(i & 511);
        unsigned int idx = (unsigned int)(best[row] & 0xFFFFFFFFull);
        float q = E[(size_t)idx * DIM + d];
        float x = X[i];
        out_q[i] = q;
        float df = q - x;
        local = fmaf(df, df, local);
    }
    #pragma unroll
    for (int off = 32; off; off >>= 1) local += __shfl_down(local, off, 64);
    int lane = t & 63, w = t >> 6;
    if (lane == 0) wsum[w] = local;
    __syncthreads();
    if (t == 0) {
        float s = wsum[0] + wsum[1] + wsum[2] + wsum[3];
        atomicAdd(accum, (double)s);
    }
}

__global__ __launch_bounds__(256)
void finalize_kernel(const unsigned long long* __restrict__ best,
                     float* __restrict__ out_idx, float* __restrict__ out_loss,
                     const double* __restrict__ accum) {
    int r = blockIdx.x * blockDim.x + threadIdx.x;
    if (r < NROWS) out_idx[r] = (float)(unsigned int)(best[r] & 0xFFFFFFFFull);
    if (r == 0) out_loss[0] = (float)(1.25 * (*accum) / 16777216.0);
}

extern "C" void kernel_launch(void* const* d_in, const int* in_sizes, int n_in,
                              void* d_out, int out_size, void* d_ws, size_t ws_size,
                              hipStream_t stream) {
    const float* X = (const float*)d_in[0];   // [32,1024,512] f32
    const float* E = (const float*)d_in[1];   // [8192,512]    f32

    float* out      = (float*)d_out;
    float* out_q    = out;                          // 16777216
    float* out_idx  = out + (size_t)NROWS * DIM;    // 32768
    float* out_loss = out_idx + NROWS;              // 1

    char* ws = (char*)d_ws;
    unsigned long long* best = (unsigned long long*)ws;
    float*  x2f   = (float*)(ws + 262144);
    double* accum = (double*)(ws + 393216);

    hipMemsetAsync(best, 0xFF, (size_t)NROWS * 8, stream);
    hipMemsetAsync(accum, 0, 8, stream);

    x2_kernel<<<NROWS / 4, 256, 0, stream>>>(X, x2f);

    if (ws_size >= WS_NEED) {
        unsigned short* Eb = (unsigned short*)(ws + 524288);
        unsigned short* Xb = (unsigned short*)(ws + 8912896);
        conv_kernel<<<(NEMB * 64) / 256, 256, 0, stream>>>(E, Eb, NEMB * 64);
        conv_kernel<<<(NROWS * 64) / 256, 256, 0, stream>>>(X, Xb, NROWS * 64);
        dim3 gridB(NROWS / BM, NEMB / BN);   // 256 x 32, x = row panels (fast)
        dist_mfma11_kernel<<<gridB, 512, 0, stream>>>(X, E, Xb, Eb, x2f, best);
    } else {
        dim3 gridB(NROWS / BM, NEMB / 128);
        dist_mfma_kernel<<<gridB, 256, 0, stream>>>(X, E, x2f, best);
    }

    gather_loss_kernel<<<2048, 256, 0, stream>>>(X, E, best, out_q, accum);
    finalize_kernel<<<NROWS / 256, 256, 0, stream>>>(best, out_idx, out_loss, accum);
}

// Round 21
// 766.922 us; speedup vs baseline: 1.4039x; 1.0301x over previous
//
#include <hip/hip_runtime.h>
#include <stdint.h>

#define NROWS 32768   // 32*1024
#define DIM   512
#define NEMB  8192

#define BM 128
#define BN 256
#define BK 32
#define MARGIN 1.0e-4f   // validated r6/r7/r9

// ws layout (fast path):
//   [0,        262144) : ull best[NROWS]   key = (f2ord(exact_d)<<32) | idx
//   [262144,   393216) : float x2f[NROWS]
//   [393216,   393224) : double loss_accum
//   [524288,  8912896) : Eb  bf16 swizzled [8192][512]
//   [8912896,42467328) : Xb  bf16 swizzled [32768][512]
#define WS_NEED 42467328ull
//
// Reference model (validated rounds 4-20, PASSED 17x): ref d = fl32(x2-2*M),
// M = k-sequential f32 FMA chain; e2 vanishes under fl32(x2+e2); argmin
// first-occurrence = lowest index on bit-equal d. bf16-hi MFMA selects
// candidates (margin 1e-4); exact f32 chain re-scores -> bit-identical.
//
// r21: compose the validated wins on r20's shape (128x256, 8 waves, 2
// blocks/CU): 3 LDS buffers (72.5KB) so the pre-barrier vmcnt(3) retires
// loads issued TWO compute phases ago (~stale, free) instead of one; drop
// the trailing lgkmcnt(0)+barrier (WAR safe: DMA(KT+2) is issued AFTER
// barrier KT, by which point all waves completed COMPUTE(KT-1) -- their
// ds_reads of buf (KT-1)%3=(KT+2)%3 finished before their MFMAs consumed
// them); T5 setprio around the 16-MFMA cluster (8-wave role diversity =
// m218b prerequisite). Sync per step: 1 barrier + 1 waitcnt (was 2+2).

typedef short bf16x8 __attribute__((ext_vector_type(8)));   // 8 bf16 (4 VGPRs)
typedef float f32x4  __attribute__((ext_vector_type(4)));

#define LDSP(p) (__attribute__((address_space(3))) unsigned int*)(p)
#define GLP(p)  (const __attribute__((address_space(1))) unsigned int*)(p)

__device__ __forceinline__ unsigned int f2ord(float f) {
    unsigned int b = __float_as_uint(f);
    return b ^ ((b & 0x80000000u) ? 0xFFFFFFFFu : 0x80000000u);
}
__device__ __forceinline__ float ord2f(unsigned int o) {
    unsigned int b = (o & 0x80000000u) ? (o ^ 0x80000000u) : ~o;
    return __uint_as_float(b);
}
__device__ __forceinline__ unsigned short f2b(float f) {   // f32 -> bf16 RNE
    unsigned int u = __float_as_uint(f);
    u += 0x7FFFu + ((u >> 16) & 1u);
    return (unsigned short)(u >> 16);
}

// exact d for (row,col): the reference-matching sequential-k f32 FMA chain.
__device__ __forceinline__ float exact_d(const float* __restrict__ X,
                                         const float* __restrict__ E,
                                         float x2r, int row, int col) {
    const float* xp = X + (size_t)row * DIM;
    const float* ep = E + (size_t)col * DIM;
    float dot = 0.f;
    #pragma unroll 4
    for (int k = 0; k < DIM; k += 4) {
        float4 a  = *(const float4*)(xp + k);
        float4 bb = *(const float4*)(ep + k);
        dot = fmaf(a.x, bb.x, dot); dot = fmaf(a.y, bb.y, dot);
        dot = fmaf(a.z, bb.z, dot); dot = fmaf(a.w, bb.w, dot);
    }
    return x2r - 2.0f * dot;
}

// ||x_row||^2 in f64, rounded to f32 — unchanged (passed 17x)
__global__ __launch_bounds__(256)
void x2_kernel(const float* __restrict__ X, float* __restrict__ x2f) {
    int w = (int)((blockIdx.x * blockDim.x + threadIdx.x) >> 6);
    int lane = threadIdx.x & 63;
    if (w >= NROWS) return;
    const float4* row = (const float4*)(X + (size_t)w * DIM);
    double s = 0.0;
    #pragma unroll
    for (int i = 0; i < 2; ++i) {
        float4 v = row[lane + i * 64];
        s += (double)v.x * v.x + (double)v.y * v.y
           + (double)v.z * v.z + (double)v.w * v.w;
    }
    #pragma unroll
    for (int off = 32; off; off >>= 1) s += __shfl_down(s, off, 64);
    if (lane == 0) x2f[w] = (float)s;
}

// f32 -> bf16 RNE convert with chunk swizzle v2 — unchanged (passed r7-r20)
__global__ __launch_bounds__(256)
void conv_kernel(const float* __restrict__ src, unsigned short* __restrict__ dst,
                 int total) {
    int tid = blockIdx.x * 256 + threadIdx.x;
    if (tid >= total) return;
    int r   = tid >> 6;
    int cg  = tid & 63;
    int seg = cg >> 2, c = cg & 3;
    const float4* s = (const float4*)(src + (size_t)r * DIM + cg * 8);
    float4 v0 = s[0], v1 = s[1];
    unsigned int w0 = (unsigned)f2b(v0.x) | ((unsigned)f2b(v0.y) << 16);
    unsigned int w1 = (unsigned)f2b(v0.z) | ((unsigned)f2b(v0.w) << 16);
    unsigned int w2 = (unsigned)f2b(v1.x) | ((unsigned)f2b(v1.y) << 16);
    unsigned int w3 = (unsigned)f2b(v1.z) | ((unsigned)f2b(v1.w) << 16);
    int dchunk = seg * 4 + (c ^ ((r >> 1) & 3));
    *(uint4*)(dst + (size_t)r * DIM + dchunk * 8) = make_uint4(w0, w1, w2, w3);
}

// 128x256 / 8 waves / 3 buffers / 1 barrier per step / counted stale vmcnt.
__global__ __launch_bounds__(512, 4)
void dist_mfma12_kernel(const float* __restrict__ X, const float* __restrict__ E,
                        const unsigned short* __restrict__ Xb,
                        const unsigned short* __restrict__ Eb,
                        const float* __restrict__ x2f,
                        unsigned long long* __restrict__ best) {
    __shared__ unsigned short As[3][BM][BK];   // 3 x 8 KB, LINEAR (DMA dest)
    __shared__ unsigned short Bs[3][BN][BK];   // 3 x 16 KB
    __shared__ unsigned int   smin[BM];

    const int t    = threadIdx.x;
    const int lane = t & 63;
    const int wid  = t >> 6;                   // 0..7
    const int wm   = (wid >> 2) * 64;          // 2 M-halves
    const int wn   = (wid & 3) * 64;           // 4 N-quarters
    const int rowBase = blockIdx.x * BM;   // x = row panels (fast) -> warm prune
    const int colBase = blockIdx.y * BN;

    if (t < BM) smin[t] = 0xFFFFFFFFu;

    // A staging: 128 rows; 8 waves x 16 rows -> 1 issue/wave.
    const char* aSrc = (const char*)Xb
        + (size_t)(rowBase + wid * 16 + (lane >> 2)) * 1024 + (size_t)(lane & 3) * 16;
    // B staging: 256 rows; rows wid*16+(lane>>2) and +128 -> 2 issues/wave.
    const char* bSrc = (const char*)Eb
        + (size_t)(colBase + wid * 16 + (lane >> 2)) * 1024 + (size_t)(lane & 3) * 16;

    // fragment read: row = base + (lane&15); logical chunk koff=(lane>>4) at
    // physical slot koff ^ ((row>>1)&3) = koff ^ ((lane>>1)&3)  [r7-validated]
    const int fswz = (((lane >> 4) ^ ((lane >> 1) & 3)) << 4);
    const int aOff = (wm + (lane & 15)) * 64 + fswz;
    const int bOff = (wn + (lane & 15)) * 64 + fswz;

    f32x4 acc[4][4] = {};

#define ISSUE_TILE(KT, BUF) do {                                               \
        const char* an_ = aSrc + (KT) * 64;                                    \
        const char* bn_ = bSrc + (KT) * 64;                                    \
        __builtin_amdgcn_global_load_lds(GLP(an_),          LDSP(&As[BUF][wid * 16][0]),       16, 0, 0); \
        __builtin_amdgcn_global_load_lds(GLP(bn_),          LDSP(&Bs[BUF][wid * 16][0]),       16, 0, 0); \
        __builtin_amdgcn_global_load_lds(GLP(bn_ + 131072), LDSP(&Bs[BUF][128 + wid * 16][0]), 16, 0, 0); \
    } while (0)

#define COMPUTE_TILE(BUF) do {                                                 \
        const char* aR_ = (const char*)&As[BUF][0][0] + aOff;                  \
        const char* bR_ = (const char*)&Bs[BUF][0][0] + bOff;                  \
        bf16x8 af_[4], bg_[4];                                                 \
        _Pragma("unroll")                                                      \
        for (int mi = 0; mi < 4; ++mi)                                         \
            af_[mi] = *(const bf16x8*)(aR_ + mi * 16 * 64);                    \
        _Pragma("unroll")                                                      \
        for (int nj = 0; nj < 4; ++nj)                                         \
            bg_[nj] = *(const bf16x8*)(bR_ + nj * 16 * 64);                    \
        __builtin_amdgcn_s_setprio(1);                                         \
        _Pragma("unroll")                                                      \
        for (int mi = 0; mi < 4; ++mi)                                         \
            _Pragma("unroll")                                                  \
            for (int nj = 0; nj < 4; ++nj)                                     \
                acc[mi][nj] = __builtin_amdgcn_mfma_f32_16x16x32_bf16(         \
                    af_[mi], bg_[nj], acc[mi][nj], 0, 0, 0);                   \
        __builtin_amdgcn_s_setprio(0);                                         \
    } while (0)

// Step KT: wait retires tile KT (issued 2 steps ago; nearly stale). Barrier
// certifies (a) all waves' tile-KT loads landed, (b) all waves finished
// COMPUTE(KT-1) -> buf (KT-1)%3 = (KT+2)%3 is free. THEN issue KT+2 into it.
// lgkmcnt(0) folded as rule-#18 insurance (drained: MFMA already consumed).
#define K_STEP(KT, WAITSTR) do {                                               \
        asm volatile("s_waitcnt vmcnt(" WAITSTR ") lgkmcnt(0)" ::: "memory");  \
        __builtin_amdgcn_s_barrier();                                          \
        if ((KT) + 2 < 16) ISSUE_TILE((KT) + 2, ((KT) + 2) % 3);               \
        COMPUTE_TILE((KT) % 3);                                                \
    } while (0)

    ISSUE_TILE(0, 0);
    ISSUE_TILE(1, 1);

    K_STEP(0,  "3");  K_STEP(1,  "3");  K_STEP(2,  "3");  K_STEP(3,  "3");
    K_STEP(4,  "3");  K_STEP(5,  "3");  K_STEP(6,  "3");  K_STEP(7,  "3");
    K_STEP(8,  "3");  K_STEP(9,  "3");  K_STEP(10, "3");  K_STEP(11, "3");
    K_STEP(12, "3");  K_STEP(13, "3");  K_STEP(14, "3");  K_STEP(15, "0");

#undef K_STEP
#undef COMPUTE_TILE
#undef ISSUE_TILE

    // ---- block-local per-row min of s~ = -2*acc (r17/r20 verbatim) ----
    #pragma unroll
    for (int mi = 0; mi < 4; ++mi)
        #pragma unroll
        for (int r = 0; r < 4; ++r) {
            float m4 = fminf(fminf(-2.f * acc[mi][0][r], -2.f * acc[mi][1][r]),
                             fminf(-2.f * acc[mi][2][r], -2.f * acc[mi][3][r]));
            unsigned u = f2ord(m4);
            #pragma unroll
            for (int sh = 1; sh < 16; sh <<= 1)
                u = min(u, (unsigned)__shfl_xor((int)u, sh, 64));
            if ((lane & 15) == 0)
                atomicMin(&smin[wm + mi * 16 + (lane >> 4) * 4 + r], u);
        }
    __syncthreads();

    // ---- candidate mask: s~ <= min(block_min, global_best - x2) + MARGIN ----
    unsigned long long mask = 0;
    #pragma unroll
    for (int mi = 0; mi < 4; ++mi)
        #pragma unroll
        for (int r = 0; r < 4; ++r) {
            int rt  = wm + mi * 16 + (lane >> 4) * 4 + r;
            int row = rowBase + rt;
            float x2v = x2f[row];
            float dg  = ord2f((unsigned)(best[row] >> 32));   // NaN if sentinel
            float th  = fminf(ord2f(smin[rt]), dg - x2v) + MARGIN;  // NaN-safe
            #pragma unroll
            for (int nj = 0; nj < 4; ++nj) {
                float s = -2.f * acc[mi][nj][r];
                if (s <= th) mask |= 1ull << (mi * 16 + nj * 4 + r);
            }
        }

    // ---- exact refine (bit-identical chain, passed 17x) ----
    while (mask) {
        int b = __builtin_ctzll(mask);
        mask &= mask - 1;
        int mi = b >> 4, nj = (b >> 2) & 3, r = b & 3;
        int row = rowBase + wm + mi * 16 + (lane >> 4) * 4 + r;
        int col = colBase + wn + nj * 16 + (lane & 15);
        float d = exact_d(X, E, x2f[row], row, col);
        unsigned long long key = ((unsigned long long)f2ord(d) << 32) | (unsigned)col;
        atomicMin(&best[row], key);
    }
}

// ---------- round-5 kernel kept as last-resort fallback (tiny ws) ----------
__global__ __launch_bounds__(256)
void dist_mfma_kernel(const float* __restrict__ X, const float* __restrict__ E,
                      const float* __restrict__ x2f,
                      unsigned long long* __restrict__ best) {
    __shared__ unsigned short Asf[BM][40];
    __shared__ unsigned short Bsf[128][40];
    __shared__ unsigned int   smin[BM];

    const int t    = threadIdx.x;
    const int lane = t & 63;
    const int wid  = t >> 6;
    const int wm   = (wid >> 1) * 64;
    const int wn   = (wid & 1) * 64;
    const int rowBase = blockIdx.x * BM;
    const int colBase = blockIdx.y * 128;

    if (t < BM) smin[t] = 0xFFFFFFFFu;

    const int srow = t >> 3;
    const int sf4  = t & 7;

    f32x4 acc[4][4] = {};
    float4 ra[4], rb[4];

    #pragma unroll
    for (int p = 0; p < 4; ++p) {
        ra[p] = *(const float4*)(X + (size_t)(rowBase + p * 32 + srow) * DIM + sf4 * 4);
        rb[p] = *(const float4*)(E + (size_t)(colBase + p * 32 + srow) * DIM + sf4 * 4);
    }

    for (int kt = 0; kt < DIM / BK; ++kt) {
        __syncthreads();
        #pragma unroll
        for (int p = 0; p < 4; ++p) {
            int r = p * 32 + srow;
            unsigned int alo = (unsigned)f2b(ra[p].x) | ((unsigned)f2b(ra[p].y) << 16);
            unsigned int ahi = (unsigned)f2b(ra[p].z) | ((unsigned)f2b(ra[p].w) << 16);
            *(uint2*)&Asf[r][sf4 * 4] = make_uint2(alo, ahi);
            unsigned int blo = (unsigned)f2b(rb[p].x) | ((unsigned)f2b(rb[p].y) << 16);
            unsigned int bhi = (unsigned)f2b(rb[p].z) | ((unsigned)f2b(rb[p].w) << 16);
            *(uint2*)&Bsf[r][sf4 * 4] = make_uint2(blo, bhi);
        }
        __syncthreads();

        if (kt + 1 < DIM / BK) {
            int k0 = (kt + 1) * BK;
            #pragma unroll
            for (int p = 0; p < 4; ++p) {
                ra[p] = *(const float4*)(X + (size_t)(rowBase + p * 32 + srow) * DIM + k0 + sf4 * 4);
                rb[p] = *(const float4*)(E + (size_t)(colBase + p * 32 + srow) * DIM + k0 + sf4 * 4);
            }
        }

        bf16x8 af[4], bg[4];
        #pragma unroll
        for (int mi = 0; mi < 4; ++mi)
            af[mi] = *(const bf16x8*)&Asf[wm + mi * 16 + (lane & 15)][(lane >> 4) * 8];
        #pragma unroll
        for (int nj = 0; nj < 4; ++nj)
            bg[nj] = *(const bf16x8*)&Bsf[wn + nj * 16 + (lane & 15)][(lane >> 4) * 8];
        #pragma unroll
        for (int mi = 0; mi < 4; ++mi)
            #pragma unroll
            for (int nj = 0; nj < 4; ++nj)
                acc[mi][nj] = __builtin_amdgcn_mfma_f32_16x16x32_bf16(
                    af[mi], bg[nj], acc[mi][nj], 0, 0, 0);
    }

    #pragma unroll
    for (int mi = 0; mi < 4; ++mi)
        #pragma unroll
        for (int r = 0; r < 4; ++r) {
            float m4 = fminf(fminf(-2.f * acc[mi][0][r], -2.f * acc[mi][1][r]),
                             fminf(-2.f * acc[mi][2][r], -2.f * acc[mi][3][r]));
            unsigned u = f2ord(m4);
            #pragma unroll
            for (int sh = 1; sh < 16; sh <<= 1)
                u = min(u, (unsigned)__shfl_xor((int)u, sh, 64));
            if ((lane & 15) == 0)
                atomicMin(&smin[wm + mi * 16 + (lane >> 4) * 4 + r], u);
        }
    __syncthreads();

    unsigned long long mask = 0;
    #pragma unroll
    for (int mi = 0; mi < 4; ++mi)
        #pragma unroll
        for (int r = 0; r < 4; ++r) {
            int rt  = wm + mi * 16 + (lane >> 4) * 4 + r;
            int row = rowBase + rt;
            float x2v = x2f[row];
            float dg  = ord2f((unsigned)(best[row] >> 32));
            float th  = fminf(ord2f(smin[rt]), dg - x2v) + 1.5e-3f;
            #pragma unroll
            for (int nj = 0; nj < 4; ++nj) {
                float s = -2.f * acc[mi][nj][r];
                if (s <= th) mask |= 1ull << (mi * 16 + nj * 4 + r);
            }
        }

    while (mask) {
        int b = __builtin_ctzll(mask);
        mask &= mask - 1;
        int mi = b >> 4, nj = (b >> 2) & 3, r = b & 3;
        int row = rowBase + wm + mi * 16 + (lane >> 4) * 4 + r;
        int col = colBase + wn + nj * 16 + (lane & 15);
        float d = exact_d(X, E, x2f[row], row, col);
        unsigned long long key = ((unsigned long long)f2ord(d) << 32) | (unsigned)col;
        atomicMin(&best[row], key);
    }
}

// gather quantized + accumulate squared-error loss — unchanged (passed 17x)
__global__ __launch_bounds__(256)
void gather_loss_kernel(const float* __restrict__ X, const float* __restrict__ E,
                        const unsigned long long* __restrict__ best,
                        float* __restrict__ out_q, double* __restrict__ accum) {
    __shared__ float wsum[4];
    const int t = threadIdx.x;
    const size_t base = (size_t)blockIdx.x * 8192;
    float local = 0.f;
    #pragma unroll 4
    for (int it = 0; it < 32; ++it) {
        size_t i = base + (size_t)it * 256 + t;
        int row = (int)(i >> 9);
        int d   = (int)(i & 511);
        unsigned int idx = (unsigned int)(best[row] & 0xFFFFFFFFull);
        float q = E[(size_t)idx * DIM + d];
        float x = X[i];
        out_q[i] = q;
        float df = q - x;
        local = fmaf(df, df, local);
    }
    #pragma unroll
    for (int off = 32; off; off >>= 1) local += __shfl_down(local, off, 64);
    int lane = t & 63, w = t >> 6;
    if (lane == 0) wsum[w] = local;
    __syncthreads();
    if (t == 0) {
        float s = wsum[0] + wsum[1] + wsum[2] + wsum[3];
        atomicAdd(accum, (double)s);
    }
}

__global__ __launch_bounds__(256)
void finalize_kernel(const unsigned long long* __restrict__ best,
                     float* __restrict__ out_idx, float* __restrict__ out_loss,
                     const double* __restrict__ accum) {
    int r = blockIdx.x * blockDim.x + threadIdx.x;
    if (r < NROWS) out_idx[r] = (float)(unsigned int)(best[r] & 0xFFFFFFFFull);
    if (r == 0) out_loss[0] = (float)(1.25 * (*accum) / 16777216.0);
}

extern "C" void kernel_launch(void* const* d_in, const int* in_sizes, int n_in,
                              void* d_out, int out_size, void* d_ws, size_t ws_size,
                              hipStream_t stream) {
    const float* X = (const float*)d_in[0];   // [32,1024,512] f32
    const float* E = (const float*)d_in[1];   // [8192,512]    f32

    float* out      = (float*)d_out;
    float* out_q    = out;                          // 16777216
    float* out_idx  = out + (size_t)NROWS * DIM;    // 32768
    float* out_loss = out_idx + NROWS;              // 1

    char* ws = (char*)d_ws;
    unsigned long long* best = (unsigned long long*)ws;
    float*  x2f   = (float*)(ws + 262144);
    double* accum = (double*)(ws + 393216);

    hipMemsetAsync(best, 0xFF, (size_t)NROWS * 8, stream);
    hipMemsetAsync(accum, 0, 8, stream);

    x2_kernel<<<NROWS / 4, 256, 0, stream>>>(X, x2f);

    if (ws_size >= WS_NEED) {
        unsigned short* Eb = (unsigned short*)(ws + 524288);
        unsigned short* Xb = (unsigned short*)(ws + 8912896);
        conv_kernel<<<(NEMB * 64) / 256, 256, 0, stream>>>(E, Eb, NEMB * 64);
        conv_kernel<<<(NROWS * 64) / 256, 256, 0, stream>>>(X, Xb, NROWS * 64);
        dim3 gridB(NROWS / BM, NEMB / BN);   // 256 x 32, x = row panels (fast)
        dist_mfma12_kernel<<<gridB, 512, 0, stream>>>(X, E, Xb, Eb, x2f, best);
    } else {
        dim3 gridB(NROWS / BM, NEMB / 128);
        dist_mfma_kernel<<<gridB, 256, 0, stream>>>(X, E, x2f, best);
    }

    gather_loss_kernel<<<2048, 256, 0, stream>>>(X, E, best, out_q, accum);
    finalize_kernel<<<NROWS / 256, 256, 0, stream>>>(best, out_idx, out_loss, accum);
}